// Round 8
// baseline (573.349 us; speedup 1.0000x reference)
//
#include <hip/hip_runtime.h>

// Problem constants (B=4, N=4096, F=64)
#define NB 4
#define NN 4096
#define NF 64
#define TSTEP 4            // j-tile steps per block (2080 = 520*4 per batch)
#define BLKS_PER_B 520

typedef __attribute__((ext_vector_type(8))) short bf16x8;   // 8 bf16 (MFMA A/B frag)
typedef __attribute__((ext_vector_type(4))) float f32x4;    // MFMA C/D frag

union S8 { unsigned short u[8]; bf16x8 v; };

__device__ __forceinline__ unsigned short f2bf(float x) {
    unsigned int uu = __builtin_bit_cast(unsigned int, x);
    uu += 0x7fffu + ((uu >> 16) & 1u);
    return (unsigned short)(uu >> 16);
}

// ---------------------------------------------------------------------------
// Fused pre-pass. Q is pre-scaled by 1/64 (leaky-relu is positively
// homogeneous and everything downstream is linear, so the 1/sqrt(N) score
// scale folds into Q). V and W_att use the "C-frag chain" k-map:
//   k = c*32 + 16*(e>>2) + 4*(lane>>4) + (e&3)
// so that swapped-QK^T C-fragments (and PV C-fragments) are directly usable
// as MFMA B-operands with no cross-lane movement.
// Unified tid space:
//   [0, 262144)            : Q/K frag conversion (Q scaled)
//   [262144, 393216)       : V frag conversion (chain k-map)
//   [393216, 393728)       : W_att frag conversion (chain k-map)
//   [393728, 918016)       : zero d_out (float4 granularity)
// ---------------------------------------------------------------------------
__global__ __launch_bounds__(256)
void prep_all(const float* __restrict__ Q, const float* __restrict__ K,
              const float* __restrict__ V, const float* __restrict__ W,
              short* __restrict__ QF, short* __restrict__ KF,
              short* __restrict__ VF, short* __restrict__ WF,
              float* __restrict__ out) {
    int tid = blockIdx.x * 256 + threadIdx.x;

    if (tid < 262144) {                       // ---- Q/K frags ----
        int sel = tid >> 17;
        int r   = tid & 0x1FFFF;
        int l  = r & 63;
        int c  = (r >> 6) & 1;
        int rg = (r >> 7) & 255;
        int b  = r >> 15;
        const float* src = sel ? K : Q;
        short*       dst = sel ? KF : QF;
        float sc = sel ? 1.0f : 0.015625f;    // 1/sqrt(4096) folded into Q

        int row = rg * 16 + (l & 15);
        int k0  = c * 32 + (l >> 4) * 8;
        const float4* s4 = (const float4*)src;
        int base4 = (b * NN + row) * 32 + (k0 >> 1);

        S8 ar, ai;
        #pragma unroll
        for (int m = 0; m < 4; ++m) {
            float4 f = s4[base4 + m];
            ar.u[2 * m]     = f2bf(f.x * sc);
            ar.u[2 * m + 1] = f2bf(f.z * sc);
            ai.u[2 * m]     = f2bf(f.y * sc);
            ai.u[2 * m + 1] = f2bf(f.w * sc);
        }
        int cid0 = ((b * 256 + rg) * 2 + c) * 2;
        *(bf16x8*)(dst + (cid0 + 0) * 512 + l * 8) = ar.v;
        *(bf16x8*)(dst + (cid0 + 1) * 512 + l * 8) = ai.v;
    } else if (tid < 393216) {                // ---- V frags (chain k-map) ----
        int r = tid - 262144;
        int l  = r & 63;
        int c  = (r >> 6) & 1;
        int ft = (r >> 7) & 3;
        int jt = (r >> 9) & 63;
        int b  = (r >> 15) & 3;

        int f  = ft * 16 + (l & 15);
        int jb = jt * 64 + c * 32 + (l >> 4) * 4;
        const float2* s2 = (const float2*)V;

        S8 ar, ai;
        #pragma unroll
        for (int e = 0; e < 8; ++e) {
            int j = jb + (e >> 2) * 16 + (e & 3);
            float2 gg = s2[(b * NN + j) * 64 + f];
            ar.u[e] = f2bf(gg.x);
            ai.u[e] = f2bf(gg.y);
        }
        int cid0 = (((b * 64 + jt) * 4 + ft) * 2 + c) * 2;
        *(bf16x8*)(VF + (cid0 + 0) * 512 + l * 8) = ar.v;
        *(bf16x8*)(VF + (cid0 + 1) * 512 + l * 8) = ai.v;
    } else if (tid < 393728) {                // ---- W_att frags (chain k-map) ----
        int r = tid - 393216;
        int l  = r & 63;
        int c  = (r >> 6) & 1;
        int gt = r >> 7;
        int grow = gt * 16 + (l & 15);
        const float* sp = W + grow * 64;
        S8 a;
        #pragma unroll
        for (int e = 0; e < 8; ++e) {
            int f = c * 32 + (e >> 2) * 16 + (l >> 4) * 4 + (e & 3);
            a.u[e] = f2bf(sp[f]);
        }
        *(bf16x8*)(WF + ((gt * 2 + c) * 64 + l) * 8) = a.v;
    } else {                                  // ---- zero d_out ----
        int r = tid - 393728;                 // 524288 float4's = 2M floats
        float4 zz = {0.f, 0.f, 0.f, 0.f};
        ((float4*)out)[r] = zz;
    }
}

// triangular inversion: largest it with it*(it+1)/2 <= g
__device__ __forceinline__ int tri_inv(int g) {
    int it = (int)((__builtin_sqrtf(8.0f * (float)g + 1.0f) - 1.0f) * 0.5f);
    while ((it + 1) * (it + 2) / 2 <= g) ++it;
    while (it * (it + 1) / 2 > g) --it;
    return it;
}

// ---------------------------------------------------------------------------
// Main kernel. 2080 blocks x 256 threads (4 waves), NO LDS. Each block does
// exactly TSTEP=4 consecutive (it,jt) steps of the flattened causal triangle.
// Per j-tile, per wave (16 q-rows):
//   S-phase : swapped complex QK^T -> mfma(K,Q) puts W[i=lane&15][j=reg-axis],
//             leaky+mask+cvt in registers -> PV B-operand frags directly.
//   PV-phase: o = mfma(V^T-frag, W-frag, o)  (O^T layout, register-local).
// Epilogue: out^T-tile = mfma(W_att-frag, O-frag) -> float4 stores (whole
// i-tile) or fp32 atomicAdd (partial segment; out pre-zeroed by prep_all).
// ---------------------------------------------------------------------------
__global__ __launch_bounds__(256, 4)
void attn_main(const short* __restrict__ QF, const short* __restrict__ KF,
               const short* __restrict__ VF, const short* __restrict__ WF,
               const float* __restrict__ batt, float* __restrict__ out) {
    int bid = blockIdx.x;
    int b   = bid / BLKS_PER_B;
    int g   = (bid % BLKS_PER_B) * TSTEP;
    int gend = g + TSTEP;

    int w   = threadIdx.x >> 6;
    int l   = threadIdx.x & 63;
    int r16 = l & 15;
    int lb  = l >> 4;

    const f32x4 z = {0.f, 0.f, 0.f, 0.f};

    while (g < gend) {
        int it   = tri_inv(g);
        int base = it * (it + 1) / 2;
        int jt0  = g - base;
        int cnt  = min(gend - g, it + 1 - jt0);
        int jt1  = jt0 + cnt;

        // Q frags (B-operand of swapped QK^T): lane holds Q[i=it*64+w*16+(l&15)][k]
        bf16x8 qf[2][2];
        {
            int rgq = it * 4 + w;
            #pragma unroll
            for (int c = 0; c < 2; ++c)
                #pragma unroll
                for (int ch = 0; ch < 2; ++ch)
                    qf[c][ch] = *(const bf16x8*)(QF + (((b * 256 + rgq) * 2 + c) * 2 + ch) * 512 + l * 8);
        }

        // O^T accumulators: o[ft][ch] holds O[i=r16][f = ft*16 + 4*lb + reg]
        f32x4 o[4][2];
        #pragma unroll
        for (int ft = 0; ft < 4; ++ft) { o[ft][0] = z; o[ft][1] = z; }

        for (int jt = jt0; jt < jt1; ++jt) {
            bool diag = (jt == it);
            S8 pa[2][2];   // PV B-operand frags [c-chunk][ch], built in registers

            #pragma unroll
            for (int ct = 0; ct < 4; ++ct) {
                bf16x8 kf[2][2];
                int rg = jt * 4 + ct;
                #pragma unroll
                for (int c = 0; c < 2; ++c)
                    #pragma unroll
                    for (int ch = 0; ch < 2; ++ch)
                        kf[c][ch] = *(const bf16x8*)(KF + (((b * 256 + rg) * 2 + c) * 2 + ch) * 512 + l * 8);

                // swapped: D[j on reg-axis][i on lane&15]
                // sr^T = Kr.Qr^T - Ki.Qi^T ; si^T = Ki.Qr^T + Kr.Qi^T
                f32x4 t1 = __builtin_amdgcn_mfma_f32_16x16x32_bf16(kf[0][0], qf[0][0], z, 0, 0, 0);
                t1 = __builtin_amdgcn_mfma_f32_16x16x32_bf16(kf[1][0], qf[1][0], t1, 0, 0, 0);
                f32x4 t2 = __builtin_amdgcn_mfma_f32_16x16x32_bf16(kf[0][1], qf[0][1], z, 0, 0, 0);
                t2 = __builtin_amdgcn_mfma_f32_16x16x32_bf16(kf[1][1], qf[1][1], t2, 0, 0, 0);
                f32x4 si = __builtin_amdgcn_mfma_f32_16x16x32_bf16(kf[0][1], qf[0][0], z, 0, 0, 0);
                si = __builtin_amdgcn_mfma_f32_16x16x32_bf16(kf[1][1], qf[1][0], si, 0, 0, 0);
                si = __builtin_amdgcn_mfma_f32_16x16x32_bf16(kf[0][0], qf[0][1], si, 0, 0, 0);
                si = __builtin_amdgcn_mfma_f32_16x16x32_bf16(kf[1][0], qf[1][1], si, 0, 0, 0);

                #pragma unroll
                for (int reg = 0; reg < 4; ++reg) {
                    float sr = t1[reg] - t2[reg];
                    float sv = si[reg];
                    float wr = fmaxf(sr, 0.f) + 0.01f * fminf(sr, 0.f);
                    float wi = fmaxf(sv, 0.f) + 0.01f * fminf(sv, 0.f);
                    if (diag) {
                        int jg = ct * 16 + lb * 4 + reg;   // j offset in 64-tile
                        int ig = w * 16 + r16;             // i offset in 64-tile
                        if (jg > ig) { wr = 0.f; wi = 0.f; }
                    }
                    pa[ct >> 1][0].u[(ct & 1) * 4 + reg] = f2bf(wr);
                    pa[ct >> 1][1].u[(ct & 1) * 4 + reg] = f2bf(wi);
                }
            }

            // PV: o = mfma(A=V^T frag, B=W frag, o), k-maps match by construction
            #pragma unroll
            for (int ft = 0; ft < 4; ++ft) {
                #pragma unroll
                for (int ch = 0; ch < 2; ++ch) {
                    int cid0 = (((b * 64 + jt) * 4 + ft) * 2 + 0) * 2 + ch;
                    bf16x8 v0 = *(const bf16x8*)(VF + cid0 * 512 + l * 8);
                    bf16x8 v1 = *(const bf16x8*)(VF + (cid0 + 2) * 512 + l * 8);
                    o[ft][ch] = __builtin_amdgcn_mfma_f32_16x16x32_bf16(v0, pa[0][ch].v, o[ft][ch], 0, 0, 0);
                    o[ft][ch] = __builtin_amdgcn_mfma_f32_16x16x32_bf16(v1, pa[1][ch].v, o[ft][ch], 0, 0, 0);
                }
            }
        }

        // ---- epilogue: out^T-tile = O @ W_att^T via mfma(W_att, O-frag) ----
        S8 ob[2][2];   // epilogue B-operand frags from O accumulators
        #pragma unroll
        for (int cc = 0; cc < 2; ++cc)
            #pragma unroll
            for (int ch = 0; ch < 2; ++ch)
                #pragma unroll
                for (int s = 0; s < 2; ++s)
                    #pragma unroll
                    for (int reg = 0; reg < 4; ++reg)
                        ob[cc][ch].u[s * 4 + reg] = f2bf(o[cc * 2 + s][ch][reg]);

        bool whole = (jt0 == 0) && (jt1 == it + 1);
        bool addb  = (jt0 == 0);
        int obase0 = ((b * NN + it * 64 + w * 16 + r16) * 64) * 2;

        #pragma unroll
        for (int gt = 0; gt < 4; ++gt) {
            bf16x8 wa0 = *(const bf16x8*)(WF + ((gt * 2 + 0) * 64 + l) * 8);
            bf16x8 wa1 = *(const bf16x8*)(WF + ((gt * 2 + 1) * 64 + l) * 8);
            float4 bq = *(const float4*)(batt + gt * 16 + lb * 4);
            float bbv[4] = {bq.x, bq.y, bq.z, bq.w};

            f32x4 a0 = __builtin_amdgcn_mfma_f32_16x16x32_bf16(wa0, ob[0][0].v, z, 0, 0, 0);
            a0 = __builtin_amdgcn_mfma_f32_16x16x32_bf16(wa1, ob[1][0].v, a0, 0, 0, 0);
            f32x4 a1 = __builtin_amdgcn_mfma_f32_16x16x32_bf16(wa0, ob[0][1].v, z, 0, 0, 0);
            a1 = __builtin_amdgcn_mfma_f32_16x16x32_bf16(wa1, ob[1][1].v, a1, 0, 0, 0);

            // lane holds out[i = r16][g = gt*16 + 4*lb + reg] for both channels
            int obase = obase0 + (gt * 16 + lb * 4) * 2;
            if (whole) {
                float4 sA = {a0[0] + bbv[0], a1[0] + bbv[0], a0[1] + bbv[1], a1[1] + bbv[1]};
                float4 sB = {a0[2] + bbv[2], a1[2] + bbv[2], a0[3] + bbv[3], a1[3] + bbv[3]};
                *(float4*)(out + obase)     = sA;
                *(float4*)(out + obase + 4) = sB;
            } else {
                #pragma unroll
                for (int reg = 0; reg < 4; ++reg) {
                    float bb = addb ? bbv[reg] : 0.f;
                    atomicAdd(out + obase + reg * 2,     a0[reg] + bb);
                    atomicAdd(out + obase + reg * 2 + 1, a1[reg] + bb);
                }
            }
        }

        g += cnt;
    }
}

// ---------------------------------------------------------------------------
extern "C" void kernel_launch(void* const* d_in, const int* in_sizes, int n_in,
                              void* d_out, int out_size, void* d_ws, size_t ws_size,
                              hipStream_t stream) {
    const float* Q  = (const float*)d_in[0];
    const float* K  = (const float*)d_in[1];
    const float* V  = (const float*)d_in[2];
    const float* W  = (const float*)d_in[3];
    const float* bA = (const float*)d_in[4];
    float* out = (float*)d_out;

    short* QF = (short*)d_ws;
    short* KF = QF + 2097152;
    short* VF = KF + 2097152;
    short* WF = VF + 2097152;

    prep_all<<<3586, 256, 0, stream>>>(Q, K, V, W, QF, KF, VF, WF, out);
    attn_main<<<NB * BLKS_PER_B, 256, 0, stream>>>(QF, KF, VF, WF, bA, out);
}

// Round 10
// 185.651 us; speedup vs baseline: 3.0883x; 3.0883x over previous
//
#include <hip/hip_runtime.h>

// Problem constants (B=4, N=4096, F=64)
#define NB 4
#define NN 4096
#define NF 64
#define TSTEP 8            // j-tile steps per block (2080 = 260*8 per batch)
#define BLKS_PER_B 260

typedef __attribute__((ext_vector_type(8))) short bf16x8;   // 8 bf16 (MFMA A/B frag)
typedef __attribute__((ext_vector_type(4))) float f32x4;    // MFMA C/D frag

union S8 { unsigned short u[8]; bf16x8 v; };

__device__ __forceinline__ unsigned short f2bf(float x) {
    unsigned int uu = __builtin_bit_cast(unsigned int, x);
    uu += 0x7fffu + ((uu >> 16) & 1u);
    return (unsigned short)(uu >> 16);
}

// ---------------------------------------------------------------------------
// Fused pre-pass. Q pre-scaled by 1/64 (= 1/sqrt(N); leaky-relu is positively
// homogeneous, rest is linear). V and W_att use the "C-frag chain" k-map
//   k = c*32 + 16*(e>>2) + 4*(lane>>4) + (e&3)
// so swapped-QK^T C-frags and PV C-frags feed the next MFMA with no
// cross-lane movement. d_out is PRE-FILLED with broadcast b_att (not zero),
// so partial-segment epilogues are pure atomic adds (bias added exactly once).
// Unified tid space:
//   [0, 262144)            : Q/K frag conversion (Q scaled)
//   [262144, 393216)       : V frag conversion (chain k-map)
//   [393216, 393728)       : W_att frag conversion (chain k-map)
//   [393728, 918016)       : fill d_out with b_att (float4 granularity)
// ---------------------------------------------------------------------------
__global__ __launch_bounds__(256)
void prep_all(const float* __restrict__ Q, const float* __restrict__ K,
              const float* __restrict__ V, const float* __restrict__ W,
              const float* __restrict__ batt,
              short* __restrict__ QF, short* __restrict__ KF,
              short* __restrict__ VF, short* __restrict__ WF,
              float* __restrict__ out) {
    int tid = blockIdx.x * 256 + threadIdx.x;

    if (tid < 262144) {                       // ---- Q/K frags ----
        int sel = tid >> 17;
        int r   = tid & 0x1FFFF;
        int l  = r & 63;
        int c  = (r >> 6) & 1;
        int rg = (r >> 7) & 255;
        int b  = r >> 15;
        const float* src = sel ? K : Q;
        short*       dst = sel ? KF : QF;
        float sc = sel ? 1.0f : 0.015625f;    // 1/sqrt(4096) folded into Q

        int row = rg * 16 + (l & 15);
        int k0  = c * 32 + (l >> 4) * 8;
        const float4* s4 = (const float4*)src;
        int base4 = (b * NN + row) * 32 + (k0 >> 1);

        S8 ar, ai;
        #pragma unroll
        for (int m = 0; m < 4; ++m) {
            float4 f = s4[base4 + m];
            ar.u[2 * m]     = f2bf(f.x * sc);
            ar.u[2 * m + 1] = f2bf(f.z * sc);
            ai.u[2 * m]     = f2bf(f.y * sc);
            ai.u[2 * m + 1] = f2bf(f.w * sc);
        }
        int cid0 = ((b * 256 + rg) * 2 + c) * 2;
        *(bf16x8*)(dst + (cid0 + 0) * 512 + l * 8) = ar.v;
        *(bf16x8*)(dst + (cid0 + 1) * 512 + l * 8) = ai.v;
    } else if (tid < 393216) {                // ---- V frags (chain k-map) ----
        int r = tid - 262144;
        int l  = r & 63;
        int c  = (r >> 6) & 1;
        int ft = (r >> 7) & 3;
        int jt = (r >> 9) & 63;
        int b  = (r >> 15) & 3;

        int f  = ft * 16 + (l & 15);
        int jb = jt * 64 + c * 32 + (l >> 4) * 4;
        const float2* s2 = (const float2*)V;

        S8 ar, ai;
        #pragma unroll
        for (int e = 0; e < 8; ++e) {
            int j = jb + (e >> 2) * 16 + (e & 3);
            float2 gg = s2[(b * NN + j) * 64 + f];
            ar.u[e] = f2bf(gg.x);
            ai.u[e] = f2bf(gg.y);
        }
        int cid0 = (((b * 64 + jt) * 4 + ft) * 2 + c) * 2;
        *(bf16x8*)(VF + (cid0 + 0) * 512 + l * 8) = ar.v;
        *(bf16x8*)(VF + (cid0 + 1) * 512 + l * 8) = ai.v;
    } else if (tid < 393728) {                // ---- W_att frags (chain k-map) ----
        int r = tid - 393216;
        int l  = r & 63;
        int c  = (r >> 6) & 1;
        int gt = r >> 7;
        int grow = gt * 16 + (l & 15);
        const float* sp = W + grow * 64;
        S8 a;
        #pragma unroll
        for (int e = 0; e < 8; ++e) {
            int f = c * 32 + (e >> 2) * 16 + (l >> 4) * 4 + (e & 3);
            a.u[e] = f2bf(sp[f]);
        }
        *(bf16x8*)(WF + ((gt * 2 + c) * 64 + l) * 8) = a.v;
    } else {                                  // ---- prefill d_out with b_att ----
        int r = tid - 393728;                 // 524288 float4's = 2M floats
        int g0 = (2 * r) & 63;                // float4 covers (g0,ch0)(g0,ch1)(g0+1,ch0)(g0+1,ch1)
        float b0 = batt[g0];
        float b1 = batt[g0 + 1];
        float4 zz = {b0, b0, b1, b1};
        ((float4*)out)[r] = zz;
    }
}

// triangular inversion: largest it with it*(it+1)/2 <= g
__device__ __forceinline__ int tri_inv(int g) {
    int it = (int)((__builtin_sqrtf(8.0f * (float)g + 1.0f) - 1.0f) * 0.5f);
    while ((it + 1) * (it + 2) / 2 <= g) ++it;
    while (it * (it + 1) / 2 > g) --it;
    return it;
}

// ---------------------------------------------------------------------------
// Main kernel. 1040 blocks x 256 threads (4 waves), no LDS, no scratch:
// all inter-MFMA handoffs stay in VGPRs (fragments built with constant-index
// vector element writes so SROA keeps them in registers — round-8 lesson:
// union element writes got PromoteAlloca'd into LDS).
// Per j-tile, per wave (16 q-rows):
//   S-phase : swapped complex QK^T (mfma(K,Q)) -> W[j on regs][i on lanes],
//             leaky+mask+cvt in registers -> PV B-operand frags directly.
//   PV-phase: o = mfma(V^T-frag, W-frag, o)   (O^T accumulator, i on lanes).
// Epilogue: acc = mfma(O-frag(A), W_attT-frag(B)) -> i on regs, g on lanes
//           -> coalesced float2 stores (whole i-tile) or contiguous fp32
//           atomicAdds (partial segment; bias comes from the out prefill).
// ---------------------------------------------------------------------------
__global__ __launch_bounds__(256, 4)
void attn_main(const short* __restrict__ QF, const short* __restrict__ KF,
               const short* __restrict__ VF, const short* __restrict__ WF,
               const float* __restrict__ batt, float* __restrict__ out) {
    int bid = blockIdx.x;
    int b   = bid / BLKS_PER_B;
    int g   = (bid % BLKS_PER_B) * TSTEP;
    int gend = g + TSTEP;

    int w   = threadIdx.x >> 6;
    int l   = threadIdx.x & 63;
    int r16 = l & 15;
    int lb  = l >> 4;

    const f32x4 z = {0.f, 0.f, 0.f, 0.f};

    while (g < gend) {
        int it   = tri_inv(g);
        int base = it * (it + 1) / 2;
        int jt0  = g - base;
        int cnt  = min(gend - g, it + 1 - jt0);
        int jt1  = jt0 + cnt;

        // Q frags (B-operand of swapped QK^T): lane holds Q[i=it*64+w*16+(l&15)][k]
        bf16x8 qf[2][2];
        {
            int rgq = it * 4 + w;
            #pragma unroll
            for (int c = 0; c < 2; ++c)
                #pragma unroll
                for (int ch = 0; ch < 2; ++ch)
                    qf[c][ch] = *(const bf16x8*)(QF + (((b * 256 + rgq) * 2 + c) * 2 + ch) * 512 + l * 8);
        }

        // O^T accumulators: o[ft][ch] holds O[i=r16][f = ft*16 + 4*lb + reg]
        f32x4 o[4][2];
        #pragma unroll
        for (int ft = 0; ft < 4; ++ft) { o[ft][0] = z; o[ft][1] = z; }

        for (int jt = jt0; jt < jt1; ++jt) {
            bool diag = (jt == it);
            bf16x8 pa0r, pa0i, pa1r, pa1i;   // PV B-frags, c-chunk 0/1, ch r/i

            #pragma unroll
            for (int ct = 0; ct < 4; ++ct) {
                bf16x8 kf[2][2];
                int rg = jt * 4 + ct;
                #pragma unroll
                for (int c = 0; c < 2; ++c)
                    #pragma unroll
                    for (int ch = 0; ch < 2; ++ch)
                        kf[c][ch] = *(const bf16x8*)(KF + (((b * 256 + rg) * 2 + c) * 2 + ch) * 512 + l * 8);

                // swapped: D[j on reg-axis][i on lane&15]
                f32x4 t1 = __builtin_amdgcn_mfma_f32_16x16x32_bf16(kf[0][0], qf[0][0], z, 0, 0, 0);
                t1 = __builtin_amdgcn_mfma_f32_16x16x32_bf16(kf[1][0], qf[1][0], t1, 0, 0, 0);
                f32x4 t2 = __builtin_amdgcn_mfma_f32_16x16x32_bf16(kf[0][1], qf[0][1], z, 0, 0, 0);
                t2 = __builtin_amdgcn_mfma_f32_16x16x32_bf16(kf[1][1], qf[1][1], t2, 0, 0, 0);
                f32x4 si = __builtin_amdgcn_mfma_f32_16x16x32_bf16(kf[0][1], qf[0][0], z, 0, 0, 0);
                si = __builtin_amdgcn_mfma_f32_16x16x32_bf16(kf[1][1], qf[1][0], si, 0, 0, 0);
                si = __builtin_amdgcn_mfma_f32_16x16x32_bf16(kf[0][0], qf[0][1], si, 0, 0, 0);
                si = __builtin_amdgcn_mfma_f32_16x16x32_bf16(kf[1][0], qf[1][1], si, 0, 0, 0);

                #pragma unroll
                for (int reg = 0; reg < 4; ++reg) {
                    float sr = t1[reg] - t2[reg];
                    float sv = si[reg];
                    float wr = fmaxf(sr, 0.f) + 0.01f * fminf(sr, 0.f);
                    float wi = fmaxf(sv, 0.f) + 0.01f * fminf(sv, 0.f);
                    if (diag) {
                        int jg = ct * 16 + lb * 4 + reg;   // j offset in 64-tile
                        int ig = w * 16 + r16;             // i offset in 64-tile
                        if (jg > ig) { wr = 0.f; wi = 0.f; }
                    }
                    short hr = (short)f2bf(wr);
                    short hi = (short)f2bf(wi);
                    int e = (ct & 1) * 4 + reg;            // constant after unroll
                    if (ct < 2) { pa0r[e] = hr; pa0i[e] = hi; }
                    else        { pa1r[e] = hr; pa1i[e] = hi; }
                }
            }

            // PV: o = mfma(A=V^T frag, B=W frag, o); k-maps match by construction
            #pragma unroll
            for (int ft = 0; ft < 4; ++ft) {
                int cid0 = (((b * 64 + jt) * 4 + ft) * 2 + 0) * 2;
                bf16x8 v0r = *(const bf16x8*)(VF + (cid0 + 0) * 512 + l * 8);
                bf16x8 v0i = *(const bf16x8*)(VF + (cid0 + 1) * 512 + l * 8);
                bf16x8 v1r = *(const bf16x8*)(VF + (cid0 + 2) * 512 + l * 8);
                bf16x8 v1i = *(const bf16x8*)(VF + (cid0 + 3) * 512 + l * 8);
                o[ft][0] = __builtin_amdgcn_mfma_f32_16x16x32_bf16(v0r, pa0r, o[ft][0], 0, 0, 0);
                o[ft][0] = __builtin_amdgcn_mfma_f32_16x16x32_bf16(v1r, pa1r, o[ft][0], 0, 0, 0);
                o[ft][1] = __builtin_amdgcn_mfma_f32_16x16x32_bf16(v0i, pa0i, o[ft][1], 0, 0, 0);
                o[ft][1] = __builtin_amdgcn_mfma_f32_16x16x32_bf16(v1i, pa1i, o[ft][1], 0, 0, 0);
            }
        }

        // ---- epilogue: acc = mfma(A=O-frag, B=W_attT-frag) -> i on regs, g on lanes ----
        bf16x8 ob[2][2];   // [c-chunk][ch]; element e=(s*4+reg) <- o[cc*2+s][ch][reg]
        #pragma unroll
        for (int cc = 0; cc < 2; ++cc)
            #pragma unroll
            for (int ch = 0; ch < 2; ++ch)
                #pragma unroll
                for (int s = 0; s < 2; ++s)
                    #pragma unroll
                    for (int reg = 0; reg < 4; ++reg)
                        ob[cc][ch][s * 4 + reg] = (short)f2bf(o[cc * 2 + s][ch][reg]);

        bool whole = (jt0 == 0) && (jt1 == it + 1);
        int i0 = it * 64 + w * 16;             // wave's first q-row

        #pragma unroll
        for (int gt = 0; gt < 4; ++gt) {
            bf16x8 wa0 = *(const bf16x8*)(WF + ((gt * 2 + 0) * 64 + l) * 8);
            bf16x8 wa1 = *(const bf16x8*)(WF + ((gt * 2 + 1) * 64 + l) * 8);

            // D[m = i-within-16 on regs][n = g on lane&15]
            f32x4 a0 = __builtin_amdgcn_mfma_f32_16x16x32_bf16(ob[0][0], wa0, z, 0, 0, 0);
            a0 = __builtin_amdgcn_mfma_f32_16x16x32_bf16(ob[1][0], wa1, a0, 0, 0, 0);
            f32x4 a1 = __builtin_amdgcn_mfma_f32_16x16x32_bf16(ob[0][1], wa0, z, 0, 0, 0);
            a1 = __builtin_amdgcn_mfma_f32_16x16x32_bf16(ob[1][1], wa1, a1, 0, 0, 0);

            int gcol = gt * 16 + r16;
            if (whole) {
                float bb = batt[gcol];
                #pragma unroll
                for (int reg = 0; reg < 4; ++reg) {
                    int irow = i0 + lb * 4 + reg;
                    float2 st = {a0[reg] + bb, a1[reg] + bb};
                    *(float2*)(out + ((b * NN + irow) * 64 + gcol) * 2) = st;
                }
            } else {
                #pragma unroll
                for (int reg = 0; reg < 4; ++reg) {
                    int irow = i0 + lb * 4 + reg;
                    int idx = ((b * NN + irow) * 64 + gcol) * 2;
                    atomicAdd(out + idx,     a0[reg]);   // bias supplied by prefill
                    atomicAdd(out + idx + 1, a1[reg]);
                }
            }
        }

        g += cnt;
    }
}

// ---------------------------------------------------------------------------
extern "C" void kernel_launch(void* const* d_in, const int* in_sizes, int n_in,
                              void* d_out, int out_size, void* d_ws, size_t ws_size,
                              hipStream_t stream) {
    const float* Q  = (const float*)d_in[0];
    const float* K  = (const float*)d_in[1];
    const float* V  = (const float*)d_in[2];
    const float* W  = (const float*)d_in[3];
    const float* bA = (const float*)d_in[4];
    float* out = (float*)d_out;

    short* QF = (short*)d_ws;
    short* KF = QF + 2097152;
    short* VF = KF + 2097152;
    short* WF = VF + 2097152;

    prep_all<<<3586, 256, 0, stream>>>(Q, K, V, W, bA, QF, KF, VF, WF, out);
    attn_main<<<NB * BLKS_PER_B, 256, 0, stream>>>(QF, KF, VF, WF, bA, out);
}